// Round 8
// baseline (221.034 us; speedup 1.0000x reference)
//
#include <hip/hip_runtime.h>
#include <cmath>

// ---------------------------------------------------------------------------
// JPEG compress (YCbCr + 2x2 chroma pool + 8x8 DCT + quantize/round).
//
// Numerics contract (VERIFIED r4/r6/r7, absmax 0.0): f32 end-to-end, every
// accumulation step is mul-then-add with TWO roundings (numpy baseline-SIMD,
// no FMA). All value-path mul/add/sub via inline asm (v_mul_f32/v_add_f32/
// v_sub_f32/v_pk_mul_f32/v_pk_add_f32) -- asm boundary blocks FMA fusion.
// v_pk_*_f32 = two independent IEEE f32 ops (RTNE) = same per-step rounding.
// fdiv/rint stay as builtins (verified).
//
// Recipe per output (DO NOT CHANGE):
//   t_c   = rn(x_c * 255)
//   y     = chain c=R,G,B: a = rn(a + rn(t_c*k_c));  X = rn(a - 128)
//   cb/cr = same chain + 128; pool ((p00+p01)+p10)+p11 * 0.25; - 128
//   dct_i = 64-step chain j row-major from 0: a = rn(a + rn(T_ij*X_j))
//   outv  = rintf( rn( rn(sc_i * dct_i) / q_i ) )
//
// R7->R8: phase-2 was LDS-streaming-bound (~3 cyc/dword issue, broadcast not
// cheaper) + unpacked VALU. Now: lane = block; X[64] copied once to VGPRs
// (lane-parallel, stride-65 conflict-free); DCT table streamed via s_load
// (SMEM pipe, K$-cached, read-only) as pre-interleaved quad rows; 2 outputs
// per v_pk instr (SGPR T-pair x op_sel-broadcast X). Outputs bounce through
// LDS Os for coalesced float4 global stores.
// ---------------------------------------------------------------------------

typedef float f2 __attribute__((ext_vector_type(2)));

namespace jc {

constexpr double c1 = 0.98078528040323044912618223613424;  // cos(1*pi/16)
constexpr double c2 = 0.92387953251128675612818318939679;
constexpr double c3 = 0.83146961230254523707878837761791;
constexpr double c4 = 0.70710678118654752440084436210485;
constexpr double c5 = 0.55557023301960222474283081394853;
constexpr double c6 = 0.38268343236508977172845998403040;
constexpr double c7 = 0.19509032201612826784828486847702;
constexpr double alpha0 = 0.70710678118654746171979706919384;  // 1.0/np.sqrt(2)

struct Tab {
  // tq4[(q*64+j)*4 + {0,1,2,3}] = T[q][j], T[q+32][j], T[q+16][j], T[q+48][j]
  // (q in 0..15, j=(x,y) row-major; T[i][j] = f32(CX[x][u]*CX[y][v]), i=(u,v))
  alignas(16) float tq4[16384];
  float sc[64];
  float yq[64];
  float cq[64];
  constexpr Tab() : tq4(), sc(), yq(), cq() {
    const double CX[8][8] = {
      {1.0,  c1,  c2,  c3,  c4,  c5,  c6,  c7},
      {1.0,  c3,  c6, -c7, -c4, -c1, -c2, -c5},
      {1.0,  c5, -c6, -c1, -c4,  c7,  c2,  c3},
      {1.0,  c7, -c2, -c5,  c4,  c3, -c6, -c1},
      {1.0, -c7, -c2,  c5,  c4, -c3, -c6,  c1},
      {1.0, -c5, -c6,  c1, -c4, -c7,  c2, -c3},
      {1.0, -c3,  c6,  c7, -c4,  c1, -c2,  c5},
      {1.0, -c1,  c2, -c3,  c4, -c5,  c6, -c7}};
    for (int q = 0; q < 16; ++q) {
      for (int j = 0; j < 64; ++j) {
        const int x = j >> 3, y = j & 7;
        const int is[4] = {q, q + 32, q + 16, q + 48};
        for (int m = 0; m < 4; ++m) {
          const int u = is[m] >> 3, v = is[m] & 7;
          tq4[(q * 64 + j) * 4 + m] = (float)(CX[x][u] * CX[y][v]);
        }
      }
    }
    for (int i = 0; i < 64; ++i) {
      const int u = i >> 3, v = i & 7;
      const double au = (u == 0) ? alpha0 : 1.0;
      const double av = (v == 0) ? alpha0 : 1.0;
      sc[i] = (float)((au * av) * 0.25);
    }
    const int YT[64] = {
      16, 11, 10, 16, 24, 40, 51, 61,
      12, 12, 14, 19, 26, 58, 60, 55,
      14, 13, 16, 24, 40, 57, 69, 56,
      14, 17, 22, 29, 51, 87, 80, 62,
      18, 22, 37, 56, 68, 109, 103, 77,
      24, 35, 55, 64, 81, 104, 113, 92,
      49, 64, 78, 87, 103, 121, 120, 101,
      72, 92, 95, 98, 112, 100, 103, 99};
    const int CT[64] = {
      17, 18, 24, 47, 99, 99, 99, 99,
      18, 21, 26, 66, 99, 99, 99, 99,
      24, 26, 56, 99, 99, 99, 99, 99,
      47, 66, 99, 99, 99, 99, 99, 99,
      99, 99, 99, 99, 99, 99, 99, 99,
      99, 99, 99, 99, 99, 99, 99, 99,
      99, 99, 99, 99, 99, 99, 99, 99,
      99, 99, 99, 99, 99, 99, 99, 99};
    for (int i = 0; i < 64; ++i) {
      yq[i] = (float)YT[i];
      cq[i] = (float)CT[i];
    }
  }
};

__device__ constexpr Tab TT;

}  // namespace jc

// ---- contraction-proof ops (asm boundary blocks FMA formation) ----
__device__ __forceinline__ float vmul(float a, float b) {
  float r; asm("v_mul_f32 %0, %1, %2" : "=v"(r) : "v"(a), "v"(b)); return r;
}
__device__ __forceinline__ float vadd(float a, float b) {
  float r; asm("v_add_f32 %0, %1, %2" : "=v"(r) : "v"(a), "v"(b)); return r;
}
__device__ __forceinline__ float vsubf(float a, float b) {
  float r; asm("v_sub_f32 %0, %1, %2" : "=v"(r) : "v"(a), "v"(b)); return r;
}
__device__ __forceinline__ float vmul_sv(float su, float v) {
  float r; asm("v_mul_f32 %0, %1, %2" : "=v"(r) : "s"(su), "v"(v)); return r;
}
// packed: T-pair (SGPRs) * broadcast X (low or high half of a VGPR pair)
__device__ __forceinline__ f2 pk_mul_lo(f2 tp, f2 x) {
  f2 r; asm("v_pk_mul_f32 %0, %1, %2 op_sel:[0,0] op_sel_hi:[1,0]"
            : "=v"(r) : "s"(tp), "v"(x)); return r;
}
__device__ __forceinline__ f2 pk_mul_hi(f2 tp, f2 x) {
  f2 r; asm("v_pk_mul_f32 %0, %1, %2 op_sel:[0,1] op_sel_hi:[1,1]"
            : "=v"(r) : "s"(tp), "v"(x)); return r;
}
__device__ __forceinline__ f2 pk_add(f2 a, f2 b) {
  f2 r; asm("v_pk_add_f32 %0, %1, %2" : "=v"(r) : "v"(a), "v"(b)); return r;
}

__device__ __forceinline__ float chro_t(float tR, float tG, float tB,
                                        float kR, float kG, float kB) {
  float a = vmul(tR, kR);
  a = vadd(a, vmul(tG, kG));
  a = vadd(a, vmul(tB, kB));
  return vadd(a, 128.0f);
}

// grid: 2048 wg x 256 thr (4 waves). wg = 64x64-px region: 64 Y + 16 Cb +
// 16 Cr blocks. Phase 2: lane = block; waves 0/1 = Y quad-groups 0/1,
// waves 2/3 = chroma (lanes 0-31) quad-groups 0/1.
__global__ __launch_bounds__(256, 4) void jpeg_kernel(const float* __restrict__ img,
                                                      float* __restrict__ out) {
  __shared__ float Xs[96][65];  // stride 65 (odd) -> conflict-free
  __shared__ float Os[96][36];  // per-round output bounce (32 slots + pad)

  const int wid = blockIdx.x;
  const int t = threadIdx.x;
  const int b = wid >> 6;   // batch
  const int r = wid & 63;   // region (8x8 grid)

  // ================= phase 1: merged staging (verified r7 code) =============
  {
    const int yb = t & 63;
    const int q = t >> 6;
    const int by = yb >> 3, bx = yb & 7;
    const int prow = (r >> 3) * 64 + by * 8 + 2 * q;
    const int pcol = (r & 7) * 64 + bx * 8;
    const float* rp = img + (size_t)b * 786432 + (size_t)prow * 512 + pcol;

    float tv[3][2][8];
#pragma unroll
    for (int c = 0; c < 3; ++c) {
#pragma unroll
      for (int rr = 0; rr < 2; ++rr) {
        const float* p0 = rp + c * 262144 + rr * 512;
        const float4 va = *(const float4*)(p0);
        const float4 vb = *(const float4*)(p0 + 4);
        tv[c][rr][0] = vmul(va.x, 255.0f);
        tv[c][rr][1] = vmul(va.y, 255.0f);
        tv[c][rr][2] = vmul(va.z, 255.0f);
        tv[c][rr][3] = vmul(va.w, 255.0f);
        tv[c][rr][4] = vmul(vb.x, 255.0f);
        tv[c][rr][5] = vmul(vb.y, 255.0f);
        tv[c][rr][6] = vmul(vb.z, 255.0f);
        tv[c][rr][7] = vmul(vb.w, 255.0f);
      }
    }
#pragma unroll
    for (int rr = 0; rr < 2; ++rr) {
#pragma unroll
      for (int y = 0; y < 8; ++y) {
        float a = vmul(tv[0][rr][y], 0.299f);
        a = vadd(a, vmul(tv[1][rr][y], 0.587f));
        a = vadd(a, vmul(tv[2][rr][y], 0.114f));
        Xs[yb][16 * q + rr * 8 + y] = vsubf(a, 128.0f);
      }
    }
    const int lcr = 4 * by + q;
#pragma unroll
    for (int pc = 0; pc < 4; ++pc) {
      const int lcc = 4 * bx + pc;
      const int crow = 64 + ((lcr >> 3) * 4 + (lcc >> 3));
      const int cell = (lcr & 7) * 8 + (lcc & 7);
      const int e = 2 * pc, o = 2 * pc + 1;
      {
        const float p00 = chro_t(tv[0][0][e], tv[1][0][e], tv[2][0][e], -0.168736f, -0.331264f, 0.5f);
        const float p01 = chro_t(tv[0][0][o], tv[1][0][o], tv[2][0][o], -0.168736f, -0.331264f, 0.5f);
        const float p10 = chro_t(tv[0][1][e], tv[1][1][e], tv[2][1][e], -0.168736f, -0.331264f, 0.5f);
        const float p11 = chro_t(tv[0][1][o], tv[1][1][o], tv[2][1][o], -0.168736f, -0.331264f, 0.5f);
        const float s = vadd(vadd(vadd(p00, p01), p10), p11);
        Xs[crow][cell] = vsubf(vmul(s, 0.25f), 128.0f);
      }
      {
        const float p00 = chro_t(tv[0][0][e], tv[1][0][e], tv[2][0][e], 0.5f, -0.418688f, -0.081312f);
        const float p01 = chro_t(tv[0][0][o], tv[1][0][o], tv[2][0][o], 0.5f, -0.418688f, -0.081312f);
        const float p10 = chro_t(tv[0][1][e], tv[1][1][e], tv[2][1][e], 0.5f, -0.418688f, -0.081312f);
        const float p11 = chro_t(tv[0][1][o], tv[1][1][o], tv[2][1][o], 0.5f, -0.418688f, -0.081312f);
        const float s = vadd(vadd(vadd(p00, p01), p10), p11);
        Xs[crow + 16][cell] = vsubf(vmul(s, 0.25f), 128.0f);
      }
    }
  }

  __syncthreads();

  // ================= phase 2: lane = block =================
  const int w = __builtin_amdgcn_readfirstlane(t >> 6);  // wave 0..3 (uniform)
  const int lane = t & 63;
  const int g = w & 1;                       // quad-group (uniform)
  const bool isY = (w < 2);                  // uniform
  const int Bl = isY ? lane : (64 + (lane & 31));
  const bool active = isY || (lane < 32);

  // X[64] of this lane's block -> VGPR pairs (ds_read2_b32, conflict-free)
  f2 X2[32];
  {
    const float* xr = Xs[Bl];
#pragma unroll
    for (int p = 0; p < 32; ++p) {
      f2 v;
      v.x = xr[2 * p];
      v.y = xr[2 * p + 1];
      X2[p] = v;
    }
  }

  const float* qt = isY ? jc::TT.yq : jc::TT.cq;

  // output base indices for the flush
  const int ry = r >> 3, rx = r & 7;
  const int ybase = b * 4096 + ry * 512 + rx * 8;
  const int cbase = b * 1024 + ry * 128 + rx * 4;

#pragma unroll
  for (int rnd = 0; rnd < 2; ++rnd) {
    // ---- compute 4 quads: q = 8g + 4*rnd + c ----
#pragma unroll
    for (int c = 0; c < 4; ++c) {
      const int q = 8 * g + 4 * rnd + c;     // uniform
      const float4* tq = (const float4*)&jc::TT.tq4[q * 256];
      f2 aA = {0.0f, 0.0f};
      f2 aB = {0.0f, 0.0f};
#pragma unroll
      for (int j = 0; j < 64; j += 2) {
        const float4 t0 = tq[j];       // uniform -> s_load
        const float4 t1 = tq[j + 1];
        const f2 x = X2[j >> 1];
        const f2 t0a = {t0.x, t0.y};
        const f2 t0b = {t0.z, t0.w};
        const f2 t1a = {t1.x, t1.y};
        const f2 t1b = {t1.z, t1.w};
        aA = pk_add(aA, pk_mul_lo(t0a, x));   // j   (even -> x.lo)
        aB = pk_add(aB, pk_mul_lo(t0b, x));
        aA = pk_add(aA, pk_mul_hi(t1a, x));   // j+1 (odd  -> x.hi)
        aB = pk_add(aB, pk_mul_hi(t1b, x));
      }
      if (active) {
        // aA = (i=q, i=q+32) -> k 0,2 ; aB = (i=q+16, i=q+48) -> k 1,3
        const int col = 4 * g + c;
        Os[Bl][col]      = rintf(__fdiv_rn(vmul_sv(jc::TT.sc[q],      aA.x), qt[q]));
        Os[Bl][8 + col]  = rintf(__fdiv_rn(vmul_sv(jc::TT.sc[q + 16], aB.x), qt[q + 16]));
        Os[Bl][16 + col] = rintf(__fdiv_rn(vmul_sv(jc::TT.sc[q + 32], aA.y), qt[q + 32]));
        Os[Bl][24 + col] = rintf(__fdiv_rn(vmul_sv(jc::TT.sc[q + 48], aB.y), qt[q + 48]));
      }
    }

    __syncthreads();

    // ---- flush: 96 blocks x 8 float4 slots, coalesced global stores ----
#pragma unroll
    for (int s = 0; s < 3; ++s) {
      const int idx = t + 256 * s;
      const int bb = idx >> 3;        // block 0..95
      const int s4 = idx & 7;         // slot4: k = s4>>1, g4 = s4&1
      const float4 v = *(const float4*)&Os[bb][4 * s4];
      const int i0 = 16 * (s4 >> 1) + 8 * (s4 & 1) + 4 * rnd;
      size_t base;
      if (bb < 64) {
        base = ((size_t)(ybase + (bb >> 3) * 64 + (bb & 7))) << 6;
      } else {
        const int typ = (bb >= 80);
        const int cb = bb - 64 - 16 * typ;
        base = (size_t)8388608 + (size_t)typ * 2097152 +
               (((size_t)(cbase + (cb >> 2) * 32 + (cb & 3))) << 6);
      }
      *(float4*)(out + base + i0) = v;
    }

    __syncthreads();  // Os reused next round
  }
}

extern "C" void kernel_launch(void* const* d_in, const int* in_sizes, int n_in,
                              void* d_out, int out_size, void* d_ws, size_t ws_size,
                              hipStream_t stream) {
  (void)in_sizes; (void)n_in; (void)d_ws; (void)ws_size; (void)out_size;
  const float* img = (const float*)d_in[0];
  float* out = (float*)d_out;
  jpeg_kernel<<<dim3(2048), dim3(256), 0, stream>>>(img, out);
}